// Round 7
// baseline (120.440 us; speedup 1.0000x reference)
//
#include <hip/hip_runtime.h>

// Sinkhorn fixed-point for fermionic canonical ensembles.
// B=2048 systems, P=64 orbitals, N_PART=32, n_iters from d_in[2].
//
// R19 = R18 (best: 59.8us kernel; 2 systems/wave SIMD-packed, VOP3P packed
// dual-f32, batched LDS loads) + HELPER WAVE AS C_k CO-PROCESSOR.
// R18 post-mortem: load batching was neutral -> stalls are dependent-op
// latency on the serial spine. Spine/iter: stage(150) -> C_k(~1800) ->
// E/Er(~240) -> sweep(~3000, bit-exact-irreducible per R16) -> update
// (~400). C_k is the only large *parallelizable* spine segment. The numpy
// accumulator tree splits by construction: acc 0..3 come only from the
// even float4s (va), acc 4..7 only from the odd ones (vb), and
// Cfull = (A01+A23) + (A45+A67) = s0 + s1. A second wave (block=128)
// computes s1 from the vb half concurrently on ANOTHER SIMD; the main
// wave computes s0 and everything else. Per-accumulator accumulation
// order and the combine tree are unchanged -> bit-identical. Handoff =
// one float/lane via LDS; the 2 barriers/iter R18 already paid become the
// producer-consumer fences (no extra barriers). Unlike R13/R15, NO serial
// work is de-shared: the sweep remains one shared chain for 2 systems.
// Helper idles at the barrier during sweep/update (cheap: heavy+light
// wave pairing per SIMD at 2048 waves / 1024 SIMDs).
// Everything else VERBATIM R18: per-system numpy op order, contract(off),
// Cody-Waite exp/log (packed v_pk_* = same IEEE op per half), ~1ulp
// rcp_nr, Er preload + volatile pins, readlane+cndmask sweep broadcast,
// packed aux-in-sweep, x2 in the load shadow.
// CANARY: absmax must be exactly 0.015625.

#pragma clang fp contract(off)

#define NPART 32
#define PORB  64

#define L2E_HI 1.44269502162933349609375f
#define L2E_LO 1.9259629911266175e-08f
#define LN2_HI 0.69314718246459960938f
#define LN2_LO -1.9046542121259175e-09f
#define LN2F   0.6931471805599453f

typedef float f32x2 __attribute__((ext_vector_type(2)));

__device__ __forceinline__ f32x2 pk(float a, float b) {
    f32x2 r; r.x = a; r.y = b; return r;
}

__device__ __forceinline__ float readlane_f(float v, int srclane) {
    return __int_as_float(__builtin_amdgcn_readlane(__float_as_int(v), srclane));
}

// reciprocal: v_rcp_f32 + one Newton step => ~0.5-1 ulp
__device__ __forceinline__ float rcp_nr(float d) {
    float r = __builtin_amdgcn_rcpf(d);
    float e = fmaf(-d, r, 1.0f);
    return fmaf(r, e, r);
}

// Packed e^arg pair with Cody-Waite correction. Per-element ops/order are
// IDENTICAL to R12's scalar exp_acc (v_pk_* = same IEEE op per half).
__device__ __forceinline__ f32x2 exp_pair(f32x2 arg) {
    const f32x2 HI = pk(L2E_HI, L2E_HI);
    const f32x2 LO = pk(L2E_LO, L2E_LO);
    const f32x2 LN = pk(LN2F,   LN2F);
    const f32x2 p    = arg * HI;                              // v_pk_mul
    const f32x2 perr = __builtin_elementwise_fma(arg, HI, -p); // v_pk_fma
    const f32x2 c    = __builtin_elementwise_fma(arg, LO, perr);
    const f32x2 cl   = c * LN;
    f32x2 e;
    e.x = __builtin_amdgcn_exp2f(p.x);
    e.y = __builtin_amdgcn_exp2f(p.y);
    return __builtin_elementwise_fma(e, cl, e);               // v_pk_fma
}

// ln(x) = log2(x)*ln2 with split constant (~1.5 ulp)
__device__ __forceinline__ float ln_acc(float x) {
    float l2 = __log2f(x);
    float p  = l2 * LN2_HI;
    float e  = fmaf(l2, LN2_HI, -p);
    return p + fmaf(l2, LN2_LO, e);
}

// shuffle within the lane's own 32-lane half
__device__ __forceinline__ float shfl32(float v, int idx, int hbit) {
    return __shfl(v, (idx & 31) | hbit, 64);
}

// numpy pairwise_sum over one system's 64 orbitals (identical to R12)
__device__ __forceinline__ float red_np(float v0, float v1, int l32, int hbit) {
    float c = v0;
    c = c + shfl32(v0, l32 + 8,  hbit);
    c = c + shfl32(v0, l32 + 16, hbit);
    c = c + shfl32(v0, l32 + 24, hbit);
    c = c + v1;
    c = c + shfl32(v1, l32 + 8,  hbit);
    c = c + shfl32(v1, l32 + 16, hbit);
    c = c + shfl32(v1, l32 + 24, hbit);
    const float ta = ((readlane_f(c, 0) + readlane_f(c, 1)) +
                      (readlane_f(c, 2) + readlane_f(c, 3))) +
                     ((readlane_f(c, 4) + readlane_f(c, 5)) +
                      (readlane_f(c, 6) + readlane_f(c, 7)));
    const float tb = ((readlane_f(c, 32) + readlane_f(c, 33)) +
                      (readlane_f(c, 34) + readlane_f(c, 35))) +
                     ((readlane_f(c, 36) + readlane_f(c, 37)) +
                      (readlane_f(c, 38) + readlane_f(c, 39)));
    return hbit ? tb : ta;
}

__global__ __launch_bounds__(2 * PORB)
__attribute__((amdgpu_waves_per_eu(2)))
void sinkhorn_kernel(
    const float* __restrict__ n_in,
    const float* __restrict__ beta_ptr,
    const int*   __restrict__ iters_ptr,
    float*       __restrict__ out)
{
    const int b    = blockIdx.x;                // pair index
    const int tid  = threadIdx.x;
    const int wv   = tid >> 6;                  // 0 = main wave, 1 = helper
    const int lane = tid & 63;
    const int l32  = lane & 31;
    const int hbit = lane & 32;                 // 0 (system A) / 32 (system B)
    const int h    = hbit >> 5;

    const float beta    = beta_ptr[0];
    const int   n_iters = iters_ptr[0];
    const float nb      = -beta;

    __shared__ __align__(16) float t_sh[2 * PORB];  // eps staging, 2 systems
    __shared__ float s1_sh[PORB];                   // helper -> main handoff

    const float kf  = (float)(l32 + 1);             // this lane's k
    const float mk  = nb * kf;
    const f32x2 mk2 = pk(mk, mk);

    if (wv == 1) {
        // ======== helper wave: accumulators a4..a7 (vb half) of C_k ======
        // Same lane->(k,half) map as the main wave; per-accumulator
        // accumulation order over i identical to R18's acc2[2],acc2[3].
        const float4* t4 = reinterpret_cast<const float4*>(t_sh);
        for (int it = 0; it < n_iters; ++it) {
            __syncthreads();                    // [1] eps staged by main
            float4 vb[8];
            #pragma unroll
            for (int i = 0; i < 8; ++i)
                vb[i] = t4[(h << 4) + 2 * i + 1];   // eps[8i+4 .. 8i+7]
            #pragma unroll
            for (int i = 0; i < 8; ++i)
                asm volatile("" : "+v"(vb[i].x), "+v"(vb[i].y), "+v"(vb[i].z), "+v"(vb[i].w));
            f32x2 acc45, acc67;
            #pragma unroll
            for (int i = 0; i < 8; ++i) {
                const f32x2 r45 = exp_pair(mk2 * pk(vb[i].x, vb[i].y));
                const f32x2 r67 = exp_pair(mk2 * pk(vb[i].z, vb[i].w));
                if (i == 0) { acc45 = r45; acc67 = r67; }
                else        { acc45 += r45; acc67 += r67; }
            }
            // s1 = (a4+a5) + (a6+a7)  -- right half of numpy's tree
            s1_sh[lane] = (acc45.x + acc45.y) + (acc67.x + acc67.y);
            __syncthreads();                    // [2] s1 ready
        }
        return;
    }

    // ======== main wave (R18 body with the vb half delegated) ========
    const float inv_beta = rcp_nr(beta);
    const f32x2 nb2 = pk(nb, nb);

    const int sysbase = (2 * b + h) * PORB;
    const float n0 = n_in[sysbase + l32];           // orbital l32
    const float n1 = n_in[sysbase + 32 + l32];      // orbital l32+32

    // ---- setup: nn, snn, ratio, eps0 (per-system values == R12) ----
    const float srt  = red_np(n0, n1, l32, hbit);
    const float isrt = rcp_nr(srt);
    const float nn0  = (n0 * isrt) * (float)NPART;
    const float nn1  = (n1 * isrt) * (float)NPART;
    const float snn  = red_np(nn0, nn1, l32, hbit);
    const float inv_snn = rcp_nr(snn);
    const float ratio0  = nn0 * rcp_nr(1.0f - nn0);
    const float ratio1  = nn1 * rcp_nr(1.0f - nn1);
    float eps0 = (-ln_acc(ratio0)) * inv_beta;
    float eps1 = (-ln_acc(ratio1)) * inv_beta;

    const f32x2 nn2    = pk(nn0, nn1);
    const f32x2 ratio2 = pk(ratio0, ratio1);
    const f32x2 one2   = pk(1.0f, 1.0f);

    for (int it = 0; it < n_iters; ++it) {
        // ---- stage both systems' eps; barrier [1] releases the helper
        // (and fences the previous iteration's LDS reads on both waves).
        t_sh[2 * hbit + l32]      = eps0;           // 2*hbit == h*64
        t_sh[2 * hbit + 32 + l32] = eps1;
        __syncthreads();                            // [1]

        // ---- batch-issue the 8 va loads (even float4s only) ----
        const float4* t4 = reinterpret_cast<const float4*>(t_sh);
        float4 va[8];
        #pragma unroll
        for (int i = 0; i < 8; ++i)
            va[i] = t4[(h << 4) + 2 * i];           // eps[8i .. 8i+3]

        // ---- aux inputs (register-only), computed IN the load shadow ----
        const f32x2 x2 = exp_pair(nb2 * pk(eps0, eps1));

        #pragma unroll
        for (int i = 0; i < 8; ++i)
            asm volatile("" : "+v"(va[i].x), "+v"(va[i].y), "+v"(va[i].z), "+v"(va[i].w));

        // ---- C_k left half: accumulators a0..a3 (order == R18) ----
        f32x2 acc01, acc23;
        #pragma unroll
        for (int i = 0; i < 8; ++i) {
            const f32x2 r01 = exp_pair(mk2 * pk(va[i].x, va[i].y));
            const f32x2 r23 = exp_pair(mk2 * pk(va[i].z, va[i].w));
            if (i == 0) { acc01 = r01; acc23 = r23; }
            else        { acc01 += r01; acc23 += r23; }
        }
        const float s0 = (acc01.x + acc01.y) + (acc23.x + acc23.y);

        __syncthreads();                            // [2] s1 ready
        // Cfull = ((a0+a1)+(a2+a3)) + ((a4+a5)+(a6+a7)) -- numpy tree
        const float Cfull = s0 + s1_sh[lane];
        // lane hbit + (k-1) holds C[k] of its system

        const float c1A = readlane_f(Cfull, 0);
        const float c1B = readlane_f(Cfull, 32);
        const float c1v = hbit ? c1B : c1A;          // per-half C[1]

        // E[i] = C[i+1]/C[i] (l32==0 junk, never consumed by live lanes)
        const float prevC = __shfl(Cfull, ((l32 - 1) & 31) | hbit, 64);
        const float E     = Cfull * rcp_nr(prevC);

        // ---- preload + pin the 31 E-gathers (R8 win) ----
        float Er[NPART];
        #pragma unroll
        for (int s = 1; s < NPART; ++s) {
            Er[s] = __shfl(E, ((l32 + 1 - s) & 31) | hbit, 64);
            asm volatile("" : "+v"(Er[s]));          // schedule pin only
        }

        // ---- fused sweep + aux (identical ops/order/rounding to R18) ----
        const float invQ0 = rcp_nr(c1v);
        f32x2 prev2;
        {
            const f32x2 a2 = (x2 * pk(invQ0, invQ0)) * one2;  // prev = 1.0
            prev2 = one2 - a2;
        }
        f32x2 y30_2 = pk(0.0f, 0.0f);
        float invQprev = invQ0;                      // invQ[s-1] carry
        float p = 1.0f;
        #pragma unroll
        for (int s = 1; s < NPART; ++s) {
            const float d = Er[s] * invQprev;
            const float m = d * p;
            p = 1.0f - m;
            const float psA = readlane_f(p, s);
            const float psB = readlane_f(p, 32 + s);
            const float psv = hbit ? psB : psA;
            const float invQs = (float)(s + 1) * rcp_nr(c1v * psv);
            // aux step s (packed; per-half == R12's (x*invQs)*prev; 1-a)
            const f32x2 a2 = (x2 * pk(invQs, invQs)) * prev2;
            prev2 = one2 - a2;
            if (s == NPART - 2) y30_2 = prev2;
            invQprev = invQs;
        }
        const float invQ31 = invQprev;               // invQ[NPART-1]
        const f32x2 Qp1_2  = prev2;
        const f32x2 Qp0_2  = y30_2 * pk(invQ31, invQ31);

        // ---- update + normalize (per-element ops identical to R12) ----
        const f32x2 q2 = (ratio2 * Qp1_2) * pk(rcp_nr(Qp0_2.x), rcp_nr(Qp0_2.y));
        const float en0 = (-ln_acc(q2.x)) * inv_beta;
        const float en1 = (-ln_acc(q2.y)) * inv_beta;

        const f32x2 w2 = nn2 * pk(en0, en1);         // {nn0*en0, nn1*en1}
        const float W = red_np(w2.x, w2.y, l32, hbit);
        const float corr = W * inv_snn;
        eps0 = en0 - corr;
        eps1 = en1 - corr;
    }

    out[sysbase + l32]      = eps0;
    out[sysbase + 32 + l32] = eps1;
}

extern "C" void kernel_launch(void* const* d_in, const int* in_sizes, int n_in,
                              void* d_out, int out_size, void* d_ws, size_t ws_size,
                              hipStream_t stream) {
    const float* n_ptr    = (const float*)d_in[0];
    const float* beta_ptr = (const float*)d_in[1];
    const int*   it_ptr   = (const int*)d_in[2];
    float*       out      = (float*)d_out;

    const int B = in_sizes[0] / PORB;   // 2048 systems, 2 per block
    sinkhorn_kernel<<<B / 2, 2 * PORB, 0, stream>>>(n_ptr, beta_ptr, it_ptr, out);
}

// Round 8
// 103.558 us; speedup vs baseline: 1.1630x; 1.1630x over previous
//
#include <hip/hip_runtime.h>

// Sinkhorn fixed-point for fermionic canonical ensembles.
// B=2048 systems, P=64 orbitals, N_PART=32, n_iters from d_in[2].
//
// R20 = R18 (best: 59.8us kernel; 2 systems/wave SIMD-packed, VOP3P packed
// dual-f32, batched LDS loads) + DRAIN ELIMINATION (schedule-only).
// R19 post-mortem: helper-wave split spilled (VGPR 132->44, scratch on the
// spine, 79.9us) -> reverted; wave-decomposition line abandoned.
// R20 removes the three compiler-forced full-drain points per iteration,
// with ZERO arithmetic change (bit-identical by construction):
//  1. __syncthreads x2 -> raw `s_waitcnt lgkmcnt(0)` asm fence. Block is
//     ONE wave: the barrier's only function is LDS write->read ordering,
//     which the explicit lgkmcnt(0) provides without s_barrier machinery.
//  2. va pins -> sched_barrier(0) after the load loop: keeps the 16
//     ds_read_b128 batched (no sinking = the R8 pathology) but lets the
//     compiler use counted lgkm waits at first use instead of a full
//     16-deep drain before any C_k compute.
//  3. Er pins -> sched_barrier(0); and Er[1] = shfl(E, l32|hbit) == E is
//     the IDENTITY (drop the shuffle). Sweep starts immediately off
//     invQ0; Er[2]'s first wait lands ~116cy into the sweep, by which
//     time the 30 pipelined bpermutes have returned. Junk-lane analysis
//     unchanged.
// Everything else VERBATIM R18: per-system numpy op order, contract(off),
// Cody-Waite exp/log (packed v_pk_* = same IEEE op per half), ~1ulp
// rcp_nr, readlane+cndmask sweep broadcast, packed aux-in-sweep, x2 in
// the load shadow, waves_per_eu(1,1), 1024 blocks x 64 threads.
// CANARY: absmax must be exactly 0.015625.

#pragma clang fp contract(off)

#define NPART 32
#define PORB  64

#define L2E_HI 1.44269502162933349609375f
#define L2E_LO 1.9259629911266175e-08f
#define LN2_HI 0.69314718246459960938f
#define LN2_LO -1.9046542121259175e-09f
#define LN2F   0.6931471805599453f

typedef float f32x2 __attribute__((ext_vector_type(2)));

__device__ __forceinline__ f32x2 pk(float a, float b) {
    f32x2 r; r.x = a; r.y = b; return r;
}

__device__ __forceinline__ float readlane_f(float v, int srclane) {
    return __int_as_float(__builtin_amdgcn_readlane(__float_as_int(v), srclane));
}

// single-wave LDS fence: orders ds_write -> ds_read for this wave without
// the s_barrier machinery __syncthreads() would emit. "memory" clobber
// stops the compiler moving LDS ops across it.
__device__ __forceinline__ void wave_lds_fence() {
    asm volatile("s_waitcnt lgkmcnt(0)" ::: "memory");
}

// reciprocal: v_rcp_f32 + one Newton step => ~0.5-1 ulp
__device__ __forceinline__ float rcp_nr(float d) {
    float r = __builtin_amdgcn_rcpf(d);
    float e = fmaf(-d, r, 1.0f);
    return fmaf(r, e, r);
}

// Packed e^arg pair with Cody-Waite correction. Per-element ops/order are
// IDENTICAL to R12's scalar exp_acc (v_pk_* = same IEEE op per half):
//   p=arg*L2E_HI; perr=fma(arg,L2E_HI,-p); c=fma(arg,L2E_LO,perr);
//   e0=exp2(p); r=fma(e0, c*LN2F, e0)
__device__ __forceinline__ f32x2 exp_pair(f32x2 arg) {
    const f32x2 HI = pk(L2E_HI, L2E_HI);
    const f32x2 LO = pk(L2E_LO, L2E_LO);
    const f32x2 LN = pk(LN2F,   LN2F);
    const f32x2 p    = arg * HI;                              // v_pk_mul
    const f32x2 perr = __builtin_elementwise_fma(arg, HI, -p); // v_pk_fma
    const f32x2 c    = __builtin_elementwise_fma(arg, LO, perr);
    const f32x2 cl   = c * LN;
    f32x2 e;
    e.x = __builtin_amdgcn_exp2f(p.x);
    e.y = __builtin_amdgcn_exp2f(p.y);
    return __builtin_elementwise_fma(e, cl, e);               // v_pk_fma
}

// ln(x) = log2(x)*ln2 with split constant (~1.5 ulp)
__device__ __forceinline__ float ln_acc(float x) {
    float l2 = __log2f(x);
    float p  = l2 * LN2_HI;
    float e  = fmaf(l2, LN2_HI, -p);
    return p + fmaf(l2, LN2_LO, e);
}

// shuffle within the lane's own 32-lane half
__device__ __forceinline__ float shfl32(float v, int idx, int hbit) {
    return __shfl(v, (idx & 31) | hbit);
}

// numpy pairwise_sum over one system's 64 orbitals (identical to R12)
__device__ __forceinline__ float red_np(float v0, float v1, int l32, int hbit) {
    float c = v0;
    c = c + shfl32(v0, l32 + 8,  hbit);
    c = c + shfl32(v0, l32 + 16, hbit);
    c = c + shfl32(v0, l32 + 24, hbit);
    c = c + v1;
    c = c + shfl32(v1, l32 + 8,  hbit);
    c = c + shfl32(v1, l32 + 16, hbit);
    c = c + shfl32(v1, l32 + 24, hbit);
    const float ta = ((readlane_f(c, 0) + readlane_f(c, 1)) +
                      (readlane_f(c, 2) + readlane_f(c, 3))) +
                     ((readlane_f(c, 4) + readlane_f(c, 5)) +
                      (readlane_f(c, 6) + readlane_f(c, 7)));
    const float tb = ((readlane_f(c, 32) + readlane_f(c, 33)) +
                      (readlane_f(c, 34) + readlane_f(c, 35))) +
                     ((readlane_f(c, 36) + readlane_f(c, 37)) +
                      (readlane_f(c, 38) + readlane_f(c, 39)));
    return hbit ? tb : ta;
}

__global__ __launch_bounds__(PORB)
__attribute__((amdgpu_waves_per_eu(1, 1)))
void sinkhorn_kernel(
    const float* __restrict__ n_in,
    const float* __restrict__ beta_ptr,
    const int*   __restrict__ iters_ptr,
    float*       __restrict__ out)
{
    const int b    = blockIdx.x;                // pair index
    const int lane = threadIdx.x;
    const int l32  = lane & 31;
    const int hbit = lane & 32;                 // 0 (system A) / 32 (system B)
    const int h    = hbit >> 5;

    const float beta    = beta_ptr[0];
    const int   n_iters = iters_ptr[0];
    const float nb      = -beta;
    const float inv_beta = rcp_nr(beta);

    __shared__ __align__(16) float t_sh[2 * PORB];  // eps staging, 2 systems

    const int sysbase = (2 * b + h) * PORB;
    const float n0 = n_in[sysbase + l32];           // orbital l32
    const float n1 = n_in[sysbase + 32 + l32];      // orbital l32+32

    // ---- setup: nn, snn, ratio, eps0 (per-system values == R12) ----
    const float srt  = red_np(n0, n1, l32, hbit);
    const float isrt = rcp_nr(srt);
    const float nn0  = (n0 * isrt) * (float)NPART;
    const float nn1  = (n1 * isrt) * (float)NPART;
    const float snn  = red_np(nn0, nn1, l32, hbit);
    const float inv_snn = rcp_nr(snn);
    const float ratio0  = nn0 * rcp_nr(1.0f - nn0);
    const float ratio1  = nn1 * rcp_nr(1.0f - nn1);
    float eps0 = (-ln_acc(ratio0)) * inv_beta;
    float eps1 = (-ln_acc(ratio1)) * inv_beta;

    const f32x2 nn2    = pk(nn0, nn1);
    const f32x2 ratio2 = pk(ratio0, ratio1);
    const f32x2 one2   = pk(1.0f, 1.0f);

    const float kf  = (float)(l32 + 1);             // this lane's k
    const float mk  = nb * kf;
    const f32x2 mk2 = pk(mk, mk);
    const f32x2 nb2 = pk(nb, nb);

    for (int it = 0; it < n_iters; ++it) {
        // ---- stage both systems' eps. Single-wave block: a raw
        // lgkmcnt(0) fence provides the write->read ordering that
        // __syncthreads provided, without s_barrier. Fence BEFORE the
        // stores also closes the WAR on the previous iteration's reads.
        wave_lds_fence();
        t_sh[2 * hbit + l32]      = eps0;           // 2*hbit == h*64
        t_sh[2 * hbit + 32 + l32] = eps1;
        wave_lds_fence();

        // ---- batch-issue ALL 16 ds_read_b128 of this half's eps tile.
        // sched_barrier(0) keeps them batched (no sinking into C_k = the
        // R8 pathology) while allowing counted per-use lgkm waits instead
        // of R18's pin-forced full drain.
        const float4* t4 = reinterpret_cast<const float4*>(t_sh);
        float4 va[8], vb[8];
        #pragma unroll
        for (int i = 0; i < 8; ++i) {
            va[i] = t4[(h << 4) + 2 * i];      // eps[8i .. 8i+3]
            vb[i] = t4[(h << 4) + 2 * i + 1];  // eps[8i+4 .. 8i+7]
        }
        __builtin_amdgcn_sched_barrier(0);

        // ---- aux inputs (register-only), computed IN the load shadow ----
        const f32x2 x2 = exp_pair(nb2 * pk(eps0, eps1));

        // ---- C_k: lane k-1 of each half builds all 8 numpy accumulators
        // (identical values/order to R18, pairwise-packed), from regs.
        // acc2[j] = {acc[2j], acc[2j+1]} of R12.
        f32x2 acc2[4];
        #pragma unroll
        for (int i = 0; i < 8; ++i) {
            const f32x2 r01 = exp_pair(mk2 * pk(va[i].x, va[i].y));
            const f32x2 r23 = exp_pair(mk2 * pk(va[i].z, va[i].w));
            const f32x2 r45 = exp_pair(mk2 * pk(vb[i].x, vb[i].y));
            const f32x2 r67 = exp_pair(mk2 * pk(vb[i].z, vb[i].w));
            if (i == 0) {
                acc2[0] = r01; acc2[1] = r23; acc2[2] = r45; acc2[3] = r67;
            } else {
                acc2[0] += r01; acc2[1] += r23; acc2[2] += r45; acc2[3] += r67;
            }
        }
        // ((a0+a1)+(a2+a3)) + ((a4+a5)+(a6+a7)) -- same tree as R12
        const float Cfull = ((acc2[0].x + acc2[0].y) + (acc2[1].x + acc2[1].y)) +
                            ((acc2[2].x + acc2[2].y) + (acc2[3].x + acc2[3].y));
        // lane hbit + (k-1) holds C[k] of its system

        const float c1A = readlane_f(Cfull, 0);
        const float c1B = readlane_f(Cfull, 32);
        const float c1v = hbit ? c1B : c1A;          // per-half C[1]

        // E[i] = C[i+1]/C[i] (l32==0 junk, never consumed by live lanes)
        const float prevC = __shfl(Cfull, ((l32 - 1) & 31) | hbit);
        const float E     = Cfull * rcp_nr(prevC);

        // ---- E-gathers: Er[1] = shfl(E, (l32)&31 | hbit) == E itself
        // (identity; same value, zero ops). Er[2..31] issued batched,
        // unpinned: sched_barrier(0) anchors issue order, waits happen
        // lazily at sweep-step uses (bpermutes return long before).
        float Er[NPART];
        Er[1] = E;
        #pragma unroll
        for (int s = 2; s < NPART; ++s) {
            Er[s] = __shfl(E, ((l32 + 1 - s) & 31) | hbit);
        }
        __builtin_amdgcn_sched_barrier(0);

        // ---- fused sweep + aux (identical ops/order/rounding to R18):
        // per-element aux ops/order identical to R12.
        const float invQ0 = rcp_nr(c1v);
        // aux step 0 (prev = 1.0 initially; g*1.0 is exact)
        f32x2 prev2;
        {
            const f32x2 a2 = (x2 * pk(invQ0, invQ0)) * one2;
            prev2 = one2 - a2;
        }
        f32x2 y30_2 = pk(0.0f, 0.0f);
        float invQprev = invQ0;                      // invQ[s-1] carry
        float p = 1.0f;
        #pragma unroll
        for (int s = 1; s < NPART; ++s) {
            const float d = Er[s] * invQprev;
            const float m = d * p;
            p = 1.0f - m;
            const float psA = readlane_f(p, s);
            const float psB = readlane_f(p, 32 + s);
            const float psv = hbit ? psB : psA;
            const float invQs = (float)(s + 1) * rcp_nr(c1v * psv);
            // aux step s (packed; per-half == R12's (x*invQs)*prev; 1-a)
            const f32x2 a2 = (x2 * pk(invQs, invQs)) * prev2;
            prev2 = one2 - a2;
            if (s == NPART - 2) y30_2 = prev2;
            invQprev = invQs;
        }
        const float invQ31 = invQprev;               // invQ[NPART-1]
        const f32x2 Qp1_2  = prev2;
        const f32x2 Qp0_2  = y30_2 * pk(invQ31, invQ31);

        // ---- update + normalize (per-element ops identical to R12) ----
        const f32x2 q2 = (ratio2 * Qp1_2) * pk(rcp_nr(Qp0_2.x), rcp_nr(Qp0_2.y));
        const float en0 = (-ln_acc(q2.x)) * inv_beta;
        const float en1 = (-ln_acc(q2.y)) * inv_beta;

        const f32x2 w2 = nn2 * pk(en0, en1);         // {nn0*en0, nn1*en1}
        const float W = red_np(w2.x, w2.y, l32, hbit);
        const float corr = W * inv_snn;
        eps0 = en0 - corr;
        eps1 = en1 - corr;
    }

    out[sysbase + l32]      = eps0;
    out[sysbase + 32 + l32] = eps1;
}

extern "C" void kernel_launch(void* const* d_in, const int* in_sizes, int n_in,
                              void* d_out, int out_size, void* d_ws, size_t ws_size,
                              hipStream_t stream) {
    const float* n_ptr    = (const float*)d_in[0];
    const float* beta_ptr = (const float*)d_in[1];
    const int*   it_ptr   = (const int*)d_in[2];
    float*       out      = (float*)d_out;

    const int B = in_sizes[0] / PORB;   // 2048 systems
    sinkhorn_kernel<<<B / 2, PORB, 0, stream>>>(n_ptr, beta_ptr, it_ptr, out);
}